// Round 1
// baseline (553.427 us; speedup 1.0000x reference)
//
#include <hip/hip_runtime.h>

#define TSTEPS 8192
#define HDIM 4096
#define PDIM 4

__device__ __forceinline__ float sigf(float x) { return 1.0f / (1.0f + __expf(-x)); }
// tanh(x) = 1 - 2/(e^(2x)+1): no inf/inf NaN at large |x|
__device__ __forceinline__ float tanhf_fast(float x) { return 1.0f - 2.0f / (__expf(2.0f * x) + 1.0f); }

__global__ void zero_kernel(float* ws, float* out) {
  int i = blockIdx.x * 256 + threadIdx.x;   // grid 256 x 256 = 65536
  ws[i] = 0.0f;                             // y0 + y1 (2 x 32768 floats)
  if (i < TSTEPS * PDIM) out[i] = 0.0f;
}

// Fused proj-LSTM layer (zero initial state): per timestep t, hidden j:
//   i,g,o gates = x[t] . W_ih[row] + b_ih + b_hh   (f gate dead: c0=0)
//   h = sig(o) * tanh(sig(i) * tanh(g));  y[t][p] += h * W_hr[p][j]
// Tiling: block = 256 thr, TB=128 timesteps, JB=64 hidden, JSPLIT=4 (grid 256).
// x and W staged TRANSPOSED (k-major) in LDS for conflict-free b128 reads.
// Micro-tile per thread: 8t x 4j x 3 gates.
template <int K>
__global__ __launch_bounds__(256, 2)
void lstm_layer(const float* __restrict__ xin, const float* __restrict__ Wih,
                const float* __restrict__ bih, const float* __restrict__ bhh,
                const float* __restrict__ Whr, float* __restrict__ yout) {
  constexpr int TB = 128, JB = 64, JSPLIT = 4;
  constexpr int KH = (K < 32) ? K : 32;   // staged k-chunk (keeps static LDS < 64 KB)
  constexpr int NKH = K / KH;
  constexpr int KQX = K / 4;              // float4 quads per x row
  constexpr int KQ = KH / 4;              // float4 quads per W row-chunk
  constexpr int WST = JB + 4;             // padded LDS stride (16B-aligned, fewer store conflicts)
  constexpr int XS = K * TB;
  constexpr int WS = 3 * KH * WST;
  constexpr int STAGE = XS + WS + 3 * JB + 4 * JB;
  constexpr int RED = 256 * 33;           // reduction scratch (stride-33: conflict-free)
  constexpr int SM = STAGE > RED ? STAGE : RED;

  __shared__ __align__(16) float smem[SM];
  float* xsT = smem;            // [K][TB]      x transposed
  float* wsT = smem + XS;       // [3][KH][WST] W transposed, gates i,g,o
  float* bsh = wsT + WS;        // [3][JB]      b_ih + b_hh
  float* hsh = bsh + 3 * JB;    // [4][JB]      W_hr slice

  const int tid = threadIdx.x;
  const int tblk = blockIdx.x / JSPLIT;
  const int jsp = blockIdx.x % JSPLIT;
  const int t0 = tblk * TB;
  const int jbase = jsp * (HDIM / JSPLIT);
  const int tg = tid >> 4;   // 0..15 -> t rows [tg*8, tg*8+8)
  const int jg = tid & 15;   // 0..15 -> j cols [jg*4, jg*4+4)

  // stage x tile transposed (once per block)
  for (int fl = tid; fl < TB * KQX; fl += 256) {
    int tl = fl / KQX, kq = fl % KQX;
    float4 v = *(const float4*)&xin[(size_t)(t0 + tl) * K + kq * 4];
    xsT[(kq * 4 + 0) * TB + tl] = v.x;
    xsT[(kq * 4 + 1) * TB + tl] = v.y;
    xsT[(kq * 4 + 2) * TB + tl] = v.z;
    xsT[(kq * 4 + 3) * TB + tl] = v.w;
  }

  float oacc[8][4];
#pragma unroll
  for (int tt = 0; tt < 8; ++tt)
#pragma unroll
    for (int p = 0; p < 4; ++p) oacc[tt][p] = 0.0f;

  for (int jt = 0; jt < HDIM / JSPLIT / JB; ++jt) {
    const int j0 = jbase + jt * JB;
    float ai[8][4], ag[8][4], ao[8][4];
#pragma unroll
    for (int tt = 0; tt < 8; ++tt)
#pragma unroll
      for (int jj = 0; jj < 4; ++jj) { ai[tt][jj] = 0.f; ag[tt][jj] = 0.f; ao[tt][jj] = 0.f; }

    for (int kh = 0; kh < NKH; ++kh) {
      __syncthreads();  // protect wsT/bsh/hsh from prior-iteration readers
      // stage W chunk transposed: gates i(+0), g(+2H), o(+3H)
      for (int fl = tid; fl < 3 * JB * KQ; fl += 256) {
        int g3 = fl / (JB * KQ);
        int rem = fl % (JB * KQ);
        int jj = rem / KQ;
        int kq = rem % KQ;
        int go = (g3 == 0) ? 0 : (g3 + 1) * HDIM;
        float4 v = *(const float4*)&Wih[(size_t)(go + j0 + jj) * K + kh * KH + kq * 4];
        wsT[(g3 * KH + kq * 4 + 0) * WST + jj] = v.x;
        wsT[(g3 * KH + kq * 4 + 1) * WST + jj] = v.y;
        wsT[(g3 * KH + kq * 4 + 2) * WST + jj] = v.z;
        wsT[(g3 * KH + kq * 4 + 3) * WST + jj] = v.w;
      }
      if (kh == 0) {
        if (tid < 3 * JB) {
          int g3 = tid / JB, jj = tid % JB;
          int go = (g3 == 0) ? 0 : (g3 + 1) * HDIM;
          bsh[g3 * JB + jj] = bih[go + j0 + jj] + bhh[go + j0 + jj];
        }
        int p = tid >> 6, jj = tid & 63;
        hsh[p * JB + jj] = Whr[p * HDIM + j0 + jj];
      }
      __syncthreads();
      // inner GEMM: 96 FMA / 5 b128 LDS reads per k-step per thread
#pragma unroll 8
      for (int kk = 0; kk < KH; ++kk) {
        const float* xr = &xsT[(kh * KH + kk) * TB + tg * 8];
        float4 xa = *(const float4*)xr;
        float4 xb = *(const float4*)(xr + 4);
        float4 wi = *(const float4*)&wsT[(0 * KH + kk) * WST + jg * 4];
        float4 wg = *(const float4*)&wsT[(1 * KH + kk) * WST + jg * 4];
        float4 wo = *(const float4*)&wsT[(2 * KH + kk) * WST + jg * 4];
        float xv[8] = {xa.x, xa.y, xa.z, xa.w, xb.x, xb.y, xb.z, xb.w};
        float wiv[4] = {wi.x, wi.y, wi.z, wi.w};
        float wgv[4] = {wg.x, wg.y, wg.z, wg.w};
        float wov[4] = {wo.x, wo.y, wo.z, wo.w};
#pragma unroll
        for (int tt = 0; tt < 8; ++tt)
#pragma unroll
          for (int jj = 0; jj < 4; ++jj) {
            ai[tt][jj] = fmaf(xv[tt], wiv[jj], ai[tt][jj]);
            ag[tt][jj] = fmaf(xv[tt], wgv[jj], ag[tt][jj]);
            ao[tt][jj] = fmaf(xv[tt], wov[jj], ao[tt][jj]);
          }
      }
    }
    // epilogue: activations + fused projection (h never hits global memory)
#pragma unroll
    for (int jj = 0; jj < 4; ++jj) {
      int jl = jg * 4 + jj;
      float bi = bsh[0 * JB + jl], bg = bsh[1 * JB + jl], bo = bsh[2 * JB + jl];
      float h0 = hsh[0 * JB + jl], h1 = hsh[1 * JB + jl];
      float h2 = hsh[2 * JB + jl], h3 = hsh[3 * JB + jl];
#pragma unroll
      for (int tt = 0; tt < 8; ++tt) {
        float c = sigf(ai[tt][jj] + bi) * tanhf_fast(ag[tt][jj] + bg);
        float h = sigf(ao[tt][jj] + bo) * tanhf_fast(c);
        oacc[tt][0] = fmaf(h, h0, oacc[tt][0]);
        oacc[tt][1] = fmaf(h, h1, oacc[tt][1]);
        oacc[tt][2] = fmaf(h, h2, oacc[tt][2]);
        oacc[tt][3] = fmaf(h, h3, oacc[tt][3]);
      }
    }
  }

  // reduce oacc across the 16 j-groups, then one atomicAdd per (t,p)
  __syncthreads();
  float* red = smem;  // stride 33 -> conflict-free
#pragma unroll
  for (int tt = 0; tt < 8; ++tt)
#pragma unroll
    for (int p = 0; p < 4; ++p) red[tid * 33 + tt * 4 + p] = oacc[tt][p];
  __syncthreads();
#pragma unroll
  for (int r = 0; r < 2; ++r) {
    int cb = r * 256 + tid;          // 512 combos = 16 tg x 8 tt x 4 p
    int tg2 = cb >> 5;
    int m = cb & 31;                 // tt*4+p
    float s = 0.0f;
#pragma unroll
    for (int j2 = 0; j2 < 16; ++j2) s += red[(tg2 * 16 + j2) * 33 + m];
    atomicAdd(&yout[(size_t)(t0 + tg2 * 8 + (m >> 2)) * PDIM + (m & 3)], s);
  }
}

extern "C" void kernel_launch(void* const* d_in, const int* in_sizes, int n_in,
                              void* d_out, int out_size, void* d_ws, size_t ws_size,
                              hipStream_t stream) {
  const float* x    = (const float*)d_in[0];
  const float* Wih0 = (const float*)d_in[1];
  const float* bih0 = (const float*)d_in[3];
  const float* bhh0 = (const float*)d_in[4];
  const float* Whr0 = (const float*)d_in[5];
  const float* Wih1 = (const float*)d_in[6];
  const float* bih1 = (const float*)d_in[8];
  const float* bhh1 = (const float*)d_in[9];
  const float* Whr1 = (const float*)d_in[10];
  const float* Wih2 = (const float*)d_in[11];
  const float* bih2 = (const float*)d_in[13];
  const float* bhh2 = (const float*)d_in[14];
  const float* Whr2 = (const float*)d_in[15];
  float* out = (float*)d_out;
  float* y0 = (float*)d_ws;            // [8192,4]
  float* y1 = y0 + TSTEPS * PDIM;      // [8192,4]

  zero_kernel<<<dim3(256), dim3(256), 0, stream>>>(y0, out);
  lstm_layer<64><<<dim3(256), dim3(256), 0, stream>>>(x,  Wih0, bih0, bhh0, Whr0, y0);
  lstm_layer<4><<<dim3(256), dim3(256), 0, stream>>>(y0, Wih1, bih1, bhh1, Whr1, y1);
  lstm_layer<4><<<dim3(256), dim3(256), 0, stream>>>(y1, Wih2, bih2, bhh2, Whr2, out);
}

// Round 2
// 512.335 us; speedup vs baseline: 1.0802x; 1.0802x over previous
//
#include <hip/hip_runtime.h>

#define TSTEPS 8192
#define HDIM 4096
#define PDIM 4

__device__ __forceinline__ float rcpf(float x) { return __builtin_amdgcn_rcpf(x); }

__global__ void zero_kernel(float* ws, float* out) {
  int i = blockIdx.x * 256 + threadIdx.x;   // grid 256 x 256 = 65536
  ws[i] = 0.0f;                             // y0 + y1 (2 x 32768 floats)
  if (i < TSTEPS * PDIM) out[i] = 0.0f;
}

// Fused proj-LSTM layer, zero initial state (f-gate dead):
//   gates i,g,o = x[t] . W_row + b;  h = sig(o)*tanh(sig(i)*tanh(g));
//   y[t][p] += h * Whr[p][j]
//
// Structure: lane = timestep. x row lives in VGPRs (K regs). The j loop is
// wave-uniform, so ALL W_ih / bias / W_hr accesses are uniform -> s_load into
// SGPRs, consumed as the scalar operand of v_fma. No LDS, no barriers, no
// bank conflicts: the vector pipe issues only FMAs + activation math.
//
// sig(a)*tanh(b) computed with ONE rcp: (1-e^{-2b}) * rcp((1+e^{-a})(1+e^{-2b})).
// Gate magnitudes here are <~10, so e^{-2b} never overflows.
template <int K, int JPB>
__global__ __launch_bounds__(256, 4)
void lstm_layer(const float* __restrict__ xin, const float* __restrict__ Wih,
                const float* __restrict__ bih, const float* __restrict__ bhh,
                const float* __restrict__ Whr, float* __restrict__ yout) {
  constexpr int JSPLIT = HDIM / JPB;          // 32 j-slices
  const int tid = threadIdx.x;                // 0..255
  const int tgrp = blockIdx.x / JSPLIT;       // 0..31
  const int jsp = blockIdx.x % JSPLIT;        // 0..31
  const int t = tgrp * 256 + tid;             // this thread's timestep
  const int j0 = jsp * JPB;

  // x row -> registers (K=64: 16 x float4; K=4: 1 x float4)
  float xr[K];
#pragma unroll
  for (int q = 0; q < K / 4; ++q) {
    float4 v = *(const float4*)&xin[(size_t)t * K + q * 4];
    xr[q * 4 + 0] = v.x; xr[q * 4 + 1] = v.y;
    xr[q * 4 + 2] = v.z; xr[q * 4 + 3] = v.w;
  }

  float o0 = 0.f, o1 = 0.f, o2 = 0.f, o3 = 0.f;

  for (int jj = 0; jj < JPB; ++jj) {
    const int j = j0 + jj;
    // PyTorch gate order i,f,g,o at row offsets 0,H,2H,3H; f is dead.
    const float* __restrict__ wi = Wih + (size_t)j * K;
    const float* __restrict__ wg = Wih + (size_t)(2 * HDIM + j) * K;
    const float* __restrict__ wo = Wih + (size_t)(3 * HDIM + j) * K;
    float gi = bih[j] + bhh[j];
    float gg = bih[2 * HDIM + j] + bhh[2 * HDIM + j];
    float go = bih[3 * HDIM + j] + bhh[3 * HDIM + j];
#pragma unroll
    for (int k = 0; k < K; ++k) {
      gi = fmaf(xr[k], wi[k], gi);   // v_fma v, s, v  (W in SGPR)
      gg = fmaf(xr[k], wg[k], gg);
      go = fmaf(xr[k], wo[k], go);
    }
    float ea = __expf(-gi);
    float eb = __expf(-2.0f * gg);
    float c = (1.0f - eb) * rcpf((1.0f + ea) * (1.0f + eb));   // sig(i)*tanh(g)
    float ec = __expf(-go);
    float ed = __expf(-2.0f * c);
    float h = (1.0f - ed) * rcpf((1.0f + ec) * (1.0f + ed));   // sig(o)*tanh(c)
    o0 = fmaf(h, Whr[0 * HDIM + j], o0);
    o1 = fmaf(h, Whr[1 * HDIM + j], o1);
    o2 = fmaf(h, Whr[2 * HDIM + j], o2);
    o3 = fmaf(h, Whr[3 * HDIM + j], o3);
  }

  float* yt = yout + (size_t)t * PDIM;
  atomicAdd(&yt[0], o0);
  atomicAdd(&yt[1], o1);
  atomicAdd(&yt[2], o2);
  atomicAdd(&yt[3], o3);
}

extern "C" void kernel_launch(void* const* d_in, const int* in_sizes, int n_in,
                              void* d_out, int out_size, void* d_ws, size_t ws_size,
                              hipStream_t stream) {
  const float* x    = (const float*)d_in[0];
  const float* Wih0 = (const float*)d_in[1];
  const float* bih0 = (const float*)d_in[3];
  const float* bhh0 = (const float*)d_in[4];
  const float* Whr0 = (const float*)d_in[5];
  const float* Wih1 = (const float*)d_in[6];
  const float* bih1 = (const float*)d_in[8];
  const float* bhh1 = (const float*)d_in[9];
  const float* Whr1 = (const float*)d_in[10];
  const float* Wih2 = (const float*)d_in[11];
  const float* bih2 = (const float*)d_in[13];
  const float* bhh2 = (const float*)d_in[14];
  const float* Whr2 = (const float*)d_in[15];
  float* out = (float*)d_out;
  float* y0 = (float*)d_ws;            // [8192,4]
  float* y1 = y0 + TSTEPS * PDIM;      // [8192,4]

  // grid: 32 t-groups x 32 j-slices = 1024 blocks -> 4 blocks/CU, 16 waves/CU
  constexpr int GRID = (TSTEPS / 256) * (HDIM / 128);

  zero_kernel<<<dim3(256), dim3(256), 0, stream>>>(y0, out);
  lstm_layer<64, 128><<<dim3(GRID), dim3(256), 0, stream>>>(x,  Wih0, bih0, bhh0, Whr0, y0);
  lstm_layer<4, 128><<<dim3(GRID), dim3(256), 0, stream>>>(y0, Wih1, bih1, bhh1, Whr1, y1);
  lstm_layer<4, 128><<<dim3(GRID), dim3(256), 0, stream>>>(y1, Wih2, bih2, bhh2, Whr2, out);
}

// Round 3
// 349.617 us; speedup vs baseline: 1.5830x; 1.4654x over previous
//
#include <hip/hip_runtime.h>

#define TSTEPS 8192
#define HDIM 4096
#define PDIM 4
#define KDIM 64

typedef __attribute__((ext_vector_type(8))) short short8;
typedef __attribute__((ext_vector_type(4))) float f32x4;

__device__ __forceinline__ float rcpf(float x) { return __builtin_amdgcn_rcpf(x); }

__global__ void zero_kernel(float* ws, float* out) {
  int i = blockIdx.x * 256 + threadIdx.x;   // grid 256 x 256 = 65536
  ws[i] = 0.0f;                             // y0 + y1 (2 x 32768 floats)
  if (i < TSTEPS * PDIM) out[i] = 0.0f;
}

__device__ __forceinline__ unsigned short bf16_rne(float f) {
  unsigned u = __float_as_uint(f);
  u += 0x7FFF + ((u >> 16) & 1);            // round-to-nearest-even
  return (unsigned short)(u >> 16);
}

// 8 consecutive fp32 -> hi/lo bf16 fragments (hi+lo represents x to ~2^-17 rel)
__device__ __forceinline__ void cvt8(const float* __restrict__ p, short8& hi, short8& lo) {
  float4 a = *(const float4*)p;
  float4 b = *(const float4*)(p + 4);
  float v[8] = {a.x, a.y, a.z, a.w, b.x, b.y, b.z, b.w};
#pragma unroll
  for (int e = 0; e < 8; ++e) {
    unsigned short h = bf16_rne(v[e]);
    float hf = __uint_as_float((unsigned)h << 16);
    hi[e] = (short)h;
    lo[e] = (short)bf16_rne(v[e] - hf);
  }
}

// Layer 0 (K=64) via MFMA 16x16x32 bf16, hi/lo split (3 passes, lo*lo dropped).
// Wave tile: 32t x 64j x 3 gates (i,g,o; f dead since c0=0). Block = 4 waves =
// 128t x 64j. A/B frags load DIRECTLY global->VGPR (per-lane, coalesced;
// W = 3MB is L2-resident, reused across all 64 t-blocks).
// A-layout (m120): A[m=lane&15][k=(lane>>4)*8+e]; C/D (m89): col=lane&15,
// row=(lane>>4)*4+reg. Epilogue: activations in C-layout -> h to LDS
// (stride 65: conflict-free) -> fused projection -> 2 atomics/thread.
__global__ __launch_bounds__(256, 2)
void lstm_layer0_mfma(const float* __restrict__ xin, const float* __restrict__ Wih,
                      const float* __restrict__ bih, const float* __restrict__ bhh,
                      const float* __restrict__ Whr, float* __restrict__ yout) {
  __shared__ float hsh[128 * 65];           // 33.3 KB
  const int tid = threadIdx.x;
  const int w = tid >> 6;
  const int lane = tid & 63;
  const int m = lane & 15;                  // row (A) / col (B,C)
  const int q = lane >> 4;                  // quad
  const int jb = blockIdx.x & 63;
  const int tb = blockIdx.x >> 6;
  const int j0 = jb * 64;
  const int t0 = tb * 128 + w * 32;

  f32x4 acc[2][4][3];
#pragma unroll
  for (int ts = 0; ts < 2; ++ts)
#pragma unroll
    for (int js = 0; js < 4; ++js)
#pragma unroll
      for (int g = 0; g < 3; ++g) acc[ts][js][g] = (f32x4){0.f, 0.f, 0.f, 0.f};

#pragma unroll
  for (int kc = 0; kc < 2; ++kc) {
    const int k0 = kc * 32 + q * 8;
    short8 ah[2], al[2];
    cvt8(xin + (size_t)(t0 + m) * KDIM + k0, ah[0], al[0]);
    cvt8(xin + (size_t)(t0 + 16 + m) * KDIM + k0, ah[1], al[1]);
#pragma unroll
    for (int js = 0; js < 4; ++js) {
      const int j = j0 + js * 16 + m;
#pragma unroll
      for (int g = 0; g < 3; ++g) {
        const int go = (g == 0) ? 0 : (g + 1) * HDIM;  // PyTorch rows i,g,o = 0,2H,3H
        short8 bh, bl;
        cvt8(Wih + (size_t)(go + j) * KDIM + k0, bh, bl);
#pragma unroll
        for (int ts = 0; ts < 2; ++ts) {
          acc[ts][js][g] = __builtin_amdgcn_mfma_f32_16x16x32_bf16(ah[ts], bh, acc[ts][js][g], 0, 0, 0);
          acc[ts][js][g] = __builtin_amdgcn_mfma_f32_16x16x32_bf16(ah[ts], bl, acc[ts][js][g], 0, 0, 0);
          acc[ts][js][g] = __builtin_amdgcn_mfma_f32_16x16x32_bf16(al[ts], bh, acc[ts][js][g], 0, 0, 0);
        }
      }
    }
  }

  // epilogue: gates -> h, stash into LDS in (t_local, j_local) layout
#pragma unroll
  for (int js = 0; js < 4; ++js) {
    const int j = j0 + js * 16 + m;
    float bi = bih[j] + bhh[j];
    float bg = bih[2 * HDIM + j] + bhh[2 * HDIM + j];
    float bo = bih[3 * HDIM + j] + bhh[3 * HDIM + j];
#pragma unroll
    for (int ts = 0; ts < 2; ++ts) {
#pragma unroll
      for (int r = 0; r < 4; ++r) {
        float gi = acc[ts][js][0][r] + bi;
        float gg = acc[ts][js][1][r] + bg;
        float go_ = acc[ts][js][2][r] + bo;
        float ea = __expf(-gi);
        float eb = __expf(-2.0f * gg);
        float c = (1.0f - eb) * rcpf((1.0f + ea) * (1.0f + eb));   // sig(i)*tanh(g)
        float ec = __expf(-go_);
        float ed = __expf(-2.0f * c);
        float h = (1.0f - ed) * rcpf((1.0f + ec) * (1.0f + ed));   // sig(o)*tanh(c)
        int tl = w * 32 + ts * 16 + q * 4 + r;
        hsh[tl * 65 + js * 16 + m] = h;
      }
    }
  }
  __syncthreads();

  // fused projection: thread = (t_local = tid&127, p-pair = 2*(tid>>7))
  const int tl = tid & 127;
  const int p0 = (tid >> 7) * 2;
  float s0 = 0.f, s1 = 0.f;
#pragma unroll
  for (int cch = 0; cch < 8; ++cch) {
    const float* wp0 = Whr + (size_t)p0 * HDIM + j0 + cch * 8;
    const float* wp1 = Whr + (size_t)(p0 + 1) * HDIM + j0 + cch * 8;
    float4 w0a = *(const float4*)wp0, w0b = *(const float4*)(wp0 + 4);
    float4 w1a = *(const float4*)wp1, w1b = *(const float4*)(wp1 + 4);
    float wa[8] = {w0a.x, w0a.y, w0a.z, w0a.w, w0b.x, w0b.y, w0b.z, w0b.w};
    float wb[8] = {w1a.x, w1a.y, w1a.z, w1a.w, w1b.x, w1b.y, w1b.z, w1b.w};
#pragma unroll
    for (int e = 0; e < 8; ++e) {
      float h = hsh[tl * 65 + cch * 8 + e];
      s0 = fmaf(h, wa[e], s0);
      s1 = fmaf(h, wb[e], s1);
    }
  }
  const int tg = tb * 128 + tl;
  atomicAdd(&yout[(size_t)tg * PDIM + p0], s0);
  atomicAdd(&yout[(size_t)tg * PDIM + p0 + 1], s1);
}

// Layers 1-2 (K=4): activation-bound; round-2 structure (lane=t, uniform j loop)
template <int K, int JPB>
__global__ __launch_bounds__(256, 4)
void lstm_layer(const float* __restrict__ xin, const float* __restrict__ Wih,
                const float* __restrict__ bih, const float* __restrict__ bhh,
                const float* __restrict__ Whr, float* __restrict__ yout) {
  constexpr int JSPLIT = HDIM / JPB;
  const int tid = threadIdx.x;
  const int tgrp = blockIdx.x / JSPLIT;
  const int jsp = blockIdx.x % JSPLIT;
  const int t = tgrp * 256 + tid;
  const int j0 = jsp * JPB;

  float xr[K];
#pragma unroll
  for (int qq = 0; qq < K / 4; ++qq) {
    float4 v = *(const float4*)&xin[(size_t)t * K + qq * 4];
    xr[qq * 4 + 0] = v.x; xr[qq * 4 + 1] = v.y;
    xr[qq * 4 + 2] = v.z; xr[qq * 4 + 3] = v.w;
  }

  float o0 = 0.f, o1 = 0.f, o2 = 0.f, o3 = 0.f;

  for (int jj = 0; jj < JPB; ++jj) {
    const int j = j0 + jj;
    const float* __restrict__ wi = Wih + (size_t)j * K;
    const float* __restrict__ wg = Wih + (size_t)(2 * HDIM + j) * K;
    const float* __restrict__ wo = Wih + (size_t)(3 * HDIM + j) * K;
    float gi = bih[j] + bhh[j];
    float gg = bih[2 * HDIM + j] + bhh[2 * HDIM + j];
    float go = bih[3 * HDIM + j] + bhh[3 * HDIM + j];
#pragma unroll
    for (int k = 0; k < K; ++k) {
      gi = fmaf(xr[k], wi[k], gi);
      gg = fmaf(xr[k], wg[k], gg);
      go = fmaf(xr[k], wo[k], go);
    }
    float ea = __expf(-gi);
    float eb = __expf(-2.0f * gg);
    float c = (1.0f - eb) * rcpf((1.0f + ea) * (1.0f + eb));
    float ec = __expf(-go);
    float ed = __expf(-2.0f * c);
    float h = (1.0f - ed) * rcpf((1.0f + ec) * (1.0f + ed));
    o0 = fmaf(h, Whr[0 * HDIM + j], o0);
    o1 = fmaf(h, Whr[1 * HDIM + j], o1);
    o2 = fmaf(h, Whr[2 * HDIM + j], o2);
    o3 = fmaf(h, Whr[3 * HDIM + j], o3);
  }

  float* yt = yout + (size_t)t * PDIM;
  atomicAdd(&yt[0], o0);
  atomicAdd(&yt[1], o1);
  atomicAdd(&yt[2], o2);
  atomicAdd(&yt[3], o3);
}

extern "C" void kernel_launch(void* const* d_in, const int* in_sizes, int n_in,
                              void* d_out, int out_size, void* d_ws, size_t ws_size,
                              hipStream_t stream) {
  const float* x    = (const float*)d_in[0];
  const float* Wih0 = (const float*)d_in[1];
  const float* bih0 = (const float*)d_in[3];
  const float* bhh0 = (const float*)d_in[4];
  const float* Whr0 = (const float*)d_in[5];
  const float* Wih1 = (const float*)d_in[6];
  const float* bih1 = (const float*)d_in[8];
  const float* bhh1 = (const float*)d_in[9];
  const float* Whr1 = (const float*)d_in[10];
  const float* Wih2 = (const float*)d_in[11];
  const float* bih2 = (const float*)d_in[13];
  const float* bhh2 = (const float*)d_in[14];
  const float* Whr2 = (const float*)d_in[15];
  float* out = (float*)d_out;
  float* y0 = (float*)d_ws;            // [8192,4]
  float* y1 = y0 + TSTEPS * PDIM;      // [8192,4]

  zero_kernel<<<dim3(256), dim3(256), 0, stream>>>(y0, out);
  // layer 0: grid = 64 t-blocks x 64 j-blocks
  lstm_layer0_mfma<<<dim3(4096), dim3(256), 0, stream>>>(x, Wih0, bih0, bhh0, Whr0, y0);
  constexpr int GRID = (TSTEPS / 256) * (HDIM / 128);
  lstm_layer<4, 128><<<dim3(GRID), dim3(256), 0, stream>>>(y0, Wih1, bih1, bhh1, Whr1, y1);
  lstm_layer<4, 128><<<dim3(GRID), dim3(256), 0, stream>>>(y1, Wih2, bih2, bhh2, Whr2, out);
}

// Round 4
// 296.389 us; speedup vs baseline: 1.8672x; 1.1796x over previous
//
#include <hip/hip_runtime.h>

#define TSTEPS 8192
#define HDIM 4096
#define PDIM 4
#define KDIM 64

typedef unsigned short u16;
typedef __attribute__((ext_vector_type(8))) short short8;
typedef __attribute__((ext_vector_type(4))) float f32x4;

#define S1 -1.44269504089f   // -log2(e)
#define S2 -2.88539008177f   // -2*log2(e)

#if __has_builtin(__builtin_amdgcn_exp2f)
#define EXP2(x) __builtin_amdgcn_exp2f(x)
#else
#define EXP2(x) exp2f(x)
#endif
__device__ __forceinline__ float rcpf(float x) { return __builtin_amdgcn_rcpf(x); }

__device__ __forceinline__ u16 bf16_rne(float f) {
  unsigned u = __float_as_uint(f);
  u += 0x7FFF + ((u >> 16) & 1);
  return (u16)(u >> 16);
}
__device__ __forceinline__ void hilo(float v, u16& h, u16& l) {
  h = bf16_rne(v);
  l = bf16_rne(v - __uint_as_float((unsigned)h << 16));
}

// ---- workspace layout (float offsets) ----
// y0:0  y1:32768  bsc:65536(12288)  c1:77824(81920)  c2:159744(81920)
// xhi:241664(262144f=524288 u16)  xlo:503808  whi:765952(393216f)  wlo:1159168
// total 1552384 floats = 6.2 MB
#define WS_Y0   0
#define WS_Y1   32768
#define WS_BSC  65536
#define WS_C1   77824
#define WS_C2   159744
#define WS_XHI  241664
#define WS_XLO  503808
#define WS_WHI  765952
#define WS_WLO  1159168

// One-shot prep: bf16 hi/lo conversion of x and W_ih0 (i,g,o rows, PRE-SCALED
// by S1/S2 so gate accumulators feed v_exp directly), scaled merged biases,
// packed per-j constant records for layers 1/2, and zeroing of y0/y1/out.
__global__ void prep_kernel(const float* __restrict__ x,
                            const float* __restrict__ Wih0, const float* __restrict__ bih0,
                            const float* __restrict__ bhh0,
                            const float* __restrict__ Wih1, const float* __restrict__ bih1,
                            const float* __restrict__ bhh1, const float* __restrict__ Whr1,
                            const float* __restrict__ Wih2, const float* __restrict__ bih2,
                            const float* __restrict__ bhh2, const float* __restrict__ Whr2,
                            float* __restrict__ ws, float* __restrict__ out) {
  const int i = blockIdx.x * 256 + threadIdx.x;
  u16* xhi = (u16*)(ws + WS_XHI);
  u16* xlo = (u16*)(ws + WS_XLO);
  u16* whi = (u16*)(ws + WS_WHI);
  u16* wlo = (u16*)(ws + WS_WLO);

  if (i < 131072) {                       // x: 131072 float4 units, unscaled
    float4 v = *(const float4*)&x[i * 4];
    float val[4] = {v.x, v.y, v.z, v.w};
    u16 h[4], l[4];
#pragma unroll
    for (int e = 0; e < 4; ++e) hilo(val[e], h[e], l[e]);
    *(ushort4*)&xhi[i * 4] = make_ushort4(h[0], h[1], h[2], h[3]);
    *(ushort4*)&xlo[i * 4] = make_ushort4(l[0], l[1], l[2], l[3]);
  } else if (i < 327680) {                // W_ih0: 196608 float4 units, scaled
    int f = i - 131072;
    int el4 = f * 4;
    int r = el4 >> 6;                     // packed row 0..12287 ([gate][j])
    int k4 = el4 & 63;
    int gate = r >> 12, jr = r & 4095;
    int src = (gate == 0) ? jr : (gate + 1) * HDIM + jr;   // i,g,o = rows 0,2H,3H
    float sc = (gate == 1) ? S2 : S1;
    float4 v = *(const float4*)&Wih0[(size_t)src * KDIM + k4];
    float val[4] = {sc * v.x, sc * v.y, sc * v.z, sc * v.w};
    u16 h[4], l[4];
#pragma unroll
    for (int e = 0; e < 4; ++e) hilo(val[e], h[e], l[e]);
    *(ushort4*)&whi[r * KDIM + k4] = make_ushort4(h[0], h[1], h[2], h[3]);
    *(ushort4*)&wlo[r * KDIM + k4] = make_ushort4(l[0], l[1], l[2], l[3]);
  } else if (i < 339968) {                // bsc[3][4096], scaled merged bias
    int f = i - 327680;
    int g = f >> 12, j = f & 4095;
    int src = (g == 0) ? j : (g + 1) * HDIM + j;
    float sc = (g == 1) ? S2 : S1;
    ws[WS_BSC + f] = sc * (bih0[src] + bhh0[src]);
  } else if (i < 348160) {                // c1/c2 packed records (20 floats/j)
    int f = i - 339968;
    const float* Wih = (f < 4096) ? Wih1 : Wih2;
    const float* bih = (f < 4096) ? bih1 : bih2;
    const float* bhh = (f < 4096) ? bhh1 : bhh2;
    const float* Whr = (f < 4096) ? Whr1 : Whr2;
    float* c = ws + ((f < 4096) ? WS_C1 : WS_C2);
    int j = f & 4095;
    float4 wi = *(const float4*)&Wih[(size_t)j * 4];
    float4 wg = *(const float4*)&Wih[(size_t)(2 * HDIM + j) * 4];
    float4 wo = *(const float4*)&Wih[(size_t)(3 * HDIM + j) * 4];
    float* cb = c + j * 20;
    *(float4*)(cb + 0)  = make_float4(S1 * wi.x, S1 * wi.y, S1 * wi.z, S1 * wi.w);
    *(float4*)(cb + 4)  = make_float4(S2 * wg.x, S2 * wg.y, S2 * wg.z, S2 * wg.w);
    *(float4*)(cb + 8)  = make_float4(S1 * wo.x, S1 * wo.y, S1 * wo.z, S1 * wo.w);
    *(float4*)(cb + 12) = make_float4(S1 * (bih[j] + bhh[j]),
                                      S2 * (bih[2 * HDIM + j] + bhh[2 * HDIM + j]),
                                      S1 * (bih[3 * HDIM + j] + bhh[3 * HDIM + j]), 0.f);
    *(float4*)(cb + 16) = make_float4(Whr[j], Whr[HDIM + j], Whr[2 * HDIM + j], Whr[3 * HDIM + j]);
  } else if (i < 446464) {                // zero y0,y1,out
    int f = i - 348160;
    if (f < 65536) ws[f] = 0.0f;
    else out[f - 65536] = 0.0f;
  }
}

// Layer 0: MFMA 16x16x32 bf16 on pre-converted, pre-scaled hi/lo fragments.
// Wave tile 32t x 64j x 3 gates; block = 4 waves = 128t x 64j; grid 64x64.
// Epilogue: gates are already exp2-args -> 4 v_exp + 2 v_rcp per h; h -> LDS
// (stride 65) -> fused projection -> 2 atomics/thread.
__global__ __launch_bounds__(256, 2)
void lstm_layer0_mfma(const u16* __restrict__ xhi, const u16* __restrict__ xlo,
                      const u16* __restrict__ whi, const u16* __restrict__ wlo,
                      const float* __restrict__ bsc, const float* __restrict__ Whr,
                      float* __restrict__ yout) {
  __shared__ float hsh[128 * 65];
  const int tid = threadIdx.x;
  const int w = tid >> 6;
  const int lane = tid & 63;
  const int m = lane & 15;
  const int q = lane >> 4;
  const int jb = blockIdx.x & 63;
  const int tb = blockIdx.x >> 6;
  const int j0 = jb * 64;
  const int t0 = tb * 128 + w * 32;

  f32x4 acc[2][4][3];
#pragma unroll
  for (int ts = 0; ts < 2; ++ts)
#pragma unroll
    for (int js = 0; js < 4; ++js)
#pragma unroll
      for (int g = 0; g < 3; ++g) acc[ts][js][g] = (f32x4){0.f, 0.f, 0.f, 0.f};

#pragma unroll
  for (int kc = 0; kc < 2; ++kc) {
    const int k0 = kc * 32 + q * 8;
    short8 ah[2], al[2];
#pragma unroll
    for (int ts = 0; ts < 2; ++ts) {
      size_t ax = (size_t)(t0 + ts * 16 + m) * KDIM + k0;
      ah[ts] = *(const short8*)&xhi[ax];
      al[ts] = *(const short8*)&xlo[ax];
    }
#pragma unroll
    for (int js = 0; js < 4; ++js) {
      const int j = j0 + js * 16 + m;
#pragma unroll
      for (int g = 0; g < 3; ++g) {
        size_t bx = (size_t)(g * HDIM + j) * KDIM + k0;
        short8 bh = *(const short8*)&whi[bx];
        short8 bl = *(const short8*)&wlo[bx];
#pragma unroll
        for (int ts = 0; ts < 2; ++ts) {
          acc[ts][js][g] = __builtin_amdgcn_mfma_f32_16x16x32_bf16(ah[ts], bh, acc[ts][js][g], 0, 0, 0);
          acc[ts][js][g] = __builtin_amdgcn_mfma_f32_16x16x32_bf16(ah[ts], bl, acc[ts][js][g], 0, 0, 0);
          acc[ts][js][g] = __builtin_amdgcn_mfma_f32_16x16x32_bf16(al[ts], bh, acc[ts][js][g], 0, 0, 0);
        }
      }
    }
  }

#pragma unroll
  for (int js = 0; js < 4; ++js) {
    const int j = j0 + js * 16 + m;
    float bi = bsc[j];
    float bg = bsc[HDIM + j];
    float bo = bsc[2 * HDIM + j];
#pragma unroll
    for (int ts = 0; ts < 2; ++ts) {
#pragma unroll
      for (int r = 0; r < 4; ++r) {
        float ea = EXP2(acc[ts][js][0][r] + bi);          // e^-i
        float eb = EXP2(acc[ts][js][1][r] + bg);          // e^-2g
        float c = (1.0f - eb) * rcpf((1.0f + ea) * (1.0f + eb));   // sig(i)tanh(g)
        float ec = EXP2(acc[ts][js][2][r] + bo);          // e^-o
        float ed = EXP2(S2 * c);                          // e^-2c
        float h = (1.0f - ed) * rcpf((1.0f + ec) * (1.0f + ed));   // sig(o)tanh(c)
        int tl = w * 32 + ts * 16 + q * 4 + r;
        hsh[tl * 65 + js * 16 + m] = h;
      }
    }
  }
  __syncthreads();

  const int tl = tid & 127;
  const int p0 = (tid >> 7) * 2;
  float s0 = 0.f, s1 = 0.f;
#pragma unroll
  for (int cch = 0; cch < 8; ++cch) {
    const float* wp0 = Whr + (size_t)p0 * HDIM + j0 + cch * 8;
    const float* wp1 = Whr + (size_t)(p0 + 1) * HDIM + j0 + cch * 8;
    float4 w0a = *(const float4*)wp0, w0b = *(const float4*)(wp0 + 4);
    float4 w1a = *(const float4*)wp1, w1b = *(const float4*)(wp1 + 4);
    float wa[8] = {w0a.x, w0a.y, w0a.z, w0a.w, w0b.x, w0b.y, w0b.z, w0b.w};
    float wb[8] = {w1a.x, w1a.y, w1a.z, w1a.w, w1b.x, w1b.y, w1b.z, w1b.w};
#pragma unroll
    for (int e = 0; e < 8; ++e) {
      float h = hsh[tl * 65 + cch * 8 + e];
      s0 = fmaf(h, wa[e], s0);
      s1 = fmaf(h, wb[e], s1);
    }
  }
  const int tg = tb * 128 + tl;
  atomicAdd(&yout[(size_t)tg * PDIM + p0], s0);
  atomicAdd(&yout[(size_t)tg * PDIM + p0 + 1], s1);
}

// Layers 1-2 (K=4): lane = timestep, wave-uniform j loop over packed 20-float
// records (pre-scaled) -> s_load + v_exp-ready gates.
__global__ __launch_bounds__(256, 4)
void lstm_small(const float* __restrict__ xin, const float* __restrict__ cpk,
                float* __restrict__ yout) {
  constexpr int JPB = 128, JSPLIT = HDIM / JPB;   // 32
  const int tid = threadIdx.x;
  const int t = (blockIdx.x / JSPLIT) * 256 + tid;
  const int j0 = (blockIdx.x % JSPLIT) * JPB;

  float4 xv = *(const float4*)&xin[(size_t)t * 4];
  float o0 = 0.f, o1 = 0.f, o2 = 0.f, o3 = 0.f;

#pragma unroll 4
  for (int jj = 0; jj < JPB; ++jj) {
    const float* cb = cpk + (size_t)(j0 + jj) * 20;
    float4 wi = *(const float4*)(cb + 0);
    float4 wg = *(const float4*)(cb + 4);
    float4 wo = *(const float4*)(cb + 8);
    float4 bb = *(const float4*)(cb + 12);
    float4 wr = *(const float4*)(cb + 16);
    float gi = bb.x, gg = bb.y, go = bb.z;
    gi = fmaf(xv.x, wi.x, gi); gi = fmaf(xv.y, wi.y, gi);
    gi = fmaf(xv.z, wi.z, gi); gi = fmaf(xv.w, wi.w, gi);
    gg = fmaf(xv.x, wg.x, gg); gg = fmaf(xv.y, wg.y, gg);
    gg = fmaf(xv.z, wg.z, gg); gg = fmaf(xv.w, wg.w, gg);
    go = fmaf(xv.x, wo.x, go); go = fmaf(xv.y, wo.y, go);
    go = fmaf(xv.z, wo.z, go); go = fmaf(xv.w, wo.w, go);
    float ea = EXP2(gi);
    float eb = EXP2(gg);
    float c = (1.0f - eb) * rcpf((1.0f + ea) * (1.0f + eb));
    float ec = EXP2(go);
    float ed = EXP2(S2 * c);
    float h = (1.0f - ed) * rcpf((1.0f + ec) * (1.0f + ed));
    o0 = fmaf(h, wr.x, o0);
    o1 = fmaf(h, wr.y, o1);
    o2 = fmaf(h, wr.z, o2);
    o3 = fmaf(h, wr.w, o3);
  }

  float* yt = yout + (size_t)t * PDIM;
  atomicAdd(&yt[0], o0);
  atomicAdd(&yt[1], o1);
  atomicAdd(&yt[2], o2);
  atomicAdd(&yt[3], o3);
}

extern "C" void kernel_launch(void* const* d_in, const int* in_sizes, int n_in,
                              void* d_out, int out_size, void* d_ws, size_t ws_size,
                              hipStream_t stream) {
  const float* x    = (const float*)d_in[0];
  const float* Wih0 = (const float*)d_in[1];
  const float* bih0 = (const float*)d_in[3];
  const float* bhh0 = (const float*)d_in[4];
  const float* Whr0 = (const float*)d_in[5];
  const float* Wih1 = (const float*)d_in[6];
  const float* bih1 = (const float*)d_in[8];
  const float* bhh1 = (const float*)d_in[9];
  const float* Whr1 = (const float*)d_in[10];
  const float* Wih2 = (const float*)d_in[11];
  const float* bih2 = (const float*)d_in[13];
  const float* bhh2 = (const float*)d_in[14];
  const float* Whr2 = (const float*)d_in[15];
  float* out = (float*)d_out;
  float* ws = (float*)d_ws;

  prep_kernel<<<dim3(1744), dim3(256), 0, stream>>>(
      x, Wih0, bih0, bhh0, Wih1, bih1, bhh1, Whr1, Wih2, bih2, bhh2, Whr2, ws, out);

  lstm_layer0_mfma<<<dim3(4096), dim3(256), 0, stream>>>(
      (const u16*)(ws + WS_XHI), (const u16*)(ws + WS_XLO),
      (const u16*)(ws + WS_WHI), (const u16*)(ws + WS_WLO),
      ws + WS_BSC, Whr0, ws + WS_Y0);

  lstm_small<<<dim3(1024), dim3(256), 0, stream>>>(ws + WS_Y0, ws + WS_C1, ws + WS_Y1);
  lstm_small<<<dim3(1024), dim3(256), 0, stream>>>(ws + WS_Y1, ws + WS_C2, out);
}